// Round 14
// baseline (540.208 us; speedup 1.0000x reference)
//
#include <hip/hip_runtime.h>

#define K_OFF   8
#define R_PAIRS 62500
#define NPAIRS  500000
#define N_IN    500000
#define N_OUT   125000
#define CIN     64
#define COUT    128
#define BN_EPS  1e-4f
#define NB2     (2 * N_OUT)          // 250,000 bins (both rulebooks, out-only)
#define SCAN_E  1024
#define NSB     245                  // ceil(250000 / 1024)
#define BM      32
#define CHUNK   32
#define OLD_TILES 8

typedef __bf16 bf16;
typedef __bf16 bf16x4 __attribute__((ext_vector_type(4)));
typedef __bf16 bf16x8 __attribute__((ext_vector_type(8)));
typedef float  f32x4  __attribute__((ext_vector_type(4)));
typedef unsigned int u32;

// bf16-z byte-offset swizzle: row-stride 1024B, inject row low bits into 16B-slot bits.
__device__ __forceinline__ int zb(int row, int col_bf16) {
    int byte = (row << 10) + (col_bf16 << 1);
    return byte ^ ((row & 7) << 4);
}

// ==================== BN statistics ====================
template<int C>
__global__ void bn_stats_kernel(const float* __restrict__ x, int n_rows,
                                float* __restrict__ sums /* [2C] */) {
    constexpr int CG = C / 4;
    int tid = blockIdx.x * blockDim.x + threadIdx.x;
    int nth = gridDim.x * blockDim.x;
    const float4* x4 = (const float4*)x;
    long n4 = (long)n_rows * CG;
    int cg = tid % CG;
    float s[4] = {0,0,0,0}, q[4] = {0,0,0,0};
    for (long i = tid; i < n4; i += nth) {
        float4 v = x4[i];
        float f[4] = {v.x, v.y, v.z, v.w};
        #pragma unroll
        for (int j = 0; j < 4; j++) { s[j] += f[j]; q[j] += f[j] * f[j]; }
    }
    __shared__ float acc[2 * C];
    for (int i = threadIdx.x; i < 2 * C; i += blockDim.x) acc[i] = 0.f;
    __syncthreads();
    #pragma unroll
    for (int j = 0; j < 4; j++) {
        atomicAdd(&acc[cg * 4 + j], s[j]);
        atomicAdd(&acc[C + cg * 4 + j], q[j]);
    }
    __syncthreads();
    for (int i = threadIdx.x; i < 2 * C; i += blockDim.x) atomicAdd(&sums[i], acc[i]);
}

template<int C>
__global__ void bn_finalize_kernel(const float* __restrict__ sums,
                                   const float* __restrict__ gamma,
                                   const float* __restrict__ beta,
                                   float inv_n, float* __restrict__ ss) {
    int c = threadIdx.x;
    if (c < C) {
        float m  = sums[c] * inv_n;
        float v  = sums[C + c] * inv_n - m * m;
        float sc = gamma[c] * rsqrtf(v + BN_EPS);
        ss[c]     = sc;
        ss[C + c] = beta[c] - m * sc;
    }
}

// BN2 finalize from 64 striped partial-sum copies
__global__ void bn_finalize2_kernel(const float* __restrict__ S /*[64][256]*/,
                                    const float* __restrict__ gamma,
                                    const float* __restrict__ beta,
                                    float* __restrict__ ss) {
    int c = threadIdx.x;   // 128
    float s = 0.f, q = 0.f;
    for (int st = 0; st < 64; st++) { s += S[st * 256 + c]; q += S[st * 256 + 128 + c]; }
    float m = s / (float)N_OUT;
    float v = q / (float)N_OUT - m * m;
    float sc = gamma[c] * rsqrtf(v + BN_EPS);
    ss[c] = sc; ss[128 + c] = beta[c] - m * sc;
}

// ==================== weight prepack (fragment order) ====================
__global__ void pack12_kernel(const float* __restrict__ W1, const float* __restrict__ W2,
                              bf16* __restrict__ Wf) {
    int idx = blockIdx.x * 256 + threadIdx.x;      // 131072
    int j = idx & 7;
    int lane = (idx >> 3) & 63;
    int fi = idx >> 9;            // 0..255
    int ks = fi >> 4, nfrag = fi & 15;
    int k512 = ks * 32 + (lane >> 4) * 8 + j;
    int koff = k512 >> 6, kc = k512 & 63;
    int c = nfrag * 16 + (lane & 15);
    const float* W = (c < 128) ? W1 : W2;
    Wf[idx] = (bf16)W[((long)koff * CIN + kc) * COUT + (c & 127)];
}

__global__ void packS_kernel(const float* __restrict__ Ws, bf16* __restrict__ Wf) {
    int idx = blockIdx.x * 256 + threadIdx.x;      // 131072
    int j = idx & 7;
    int lane = (idx >> 3) & 63;
    int fi = idx >> 9;            // 0..255
    int ksg = fi >> 3, nfrag = fi & 7;
    int k1024 = ksg * 32 + (lane >> 4) * 8 + j;
    int koff = k1024 >> 7, kc = k1024 & 127;
    int c = nfrag * 16 + (lane & 15);
    Wf[idx] = (bf16)Ws[((long)koff * COUT + kc) * COUT + c];
}

// ==================== merged hist over both rulebooks (out-only, 250k bins) ========
__global__ void hist2_kernel(const int* __restrict__ o1, const int* __restrict__ os,
                             u32* __restrict__ counts) {
    int p = blockIdx.x * blockDim.x + threadIdx.x;
    int stride = gridDim.x * blockDim.x;
    for (; p < 2 * NPAIRS; p += stride) {
        int bin = (p < NPAIRS) ? o1[p] : (N_OUT + os[p - NPAIRS]);
        atomicAdd(&counts[bin], 1u);
    }
}

// ==================== 3-level scan, 1024 elems/block ====================
__global__ void scan1_kernel(const u32* __restrict__ counts, u32* __restrict__ bsum, int n) {
    __shared__ u32 sd[256];
    int tid = threadIdx.x;
    int base = blockIdx.x * SCAN_E + tid * 4;
    u32 s = 0;
    #pragma unroll
    for (int j = 0; j < 4; j++) { int i = base + j; if (i < n) s += counts[i]; }
    sd[tid] = s; __syncthreads();
    for (int st = 128; st > 0; st >>= 1) { if (tid < st) sd[tid] += sd[tid + st]; __syncthreads(); }
    if (tid == 0) bsum[blockIdx.x] = sd[0];
}

__global__ void scan2_kernel(u32* __restrict__ bsum, u32* __restrict__ starts, int nb, int n) {
    __shared__ u32 sd[256];
    int tid = threadIdx.x;
    u32 v = (tid < nb) ? bsum[tid] : 0;
    sd[tid] = v; __syncthreads();
    for (int st = 1; st < 256; st <<= 1) {
        u32 t = (tid >= st) ? sd[tid - st] : 0;
        __syncthreads();
        sd[tid] += t;
        __syncthreads();
    }
    if (tid < nb) bsum[tid] = sd[tid] - v;     // exclusive
    if (tid == 255) starts[n] = sd[255];       // total
}

__global__ void scan3_kernel(const u32* __restrict__ counts, const u32* __restrict__ bsum,
                             u32* __restrict__ starts, int n) {
    __shared__ u32 sd[256];
    int tid = threadIdx.x;
    int base = blockIdx.x * SCAN_E + tid * 4;
    u32 v[4]; u32 s = 0;
    #pragma unroll
    for (int j = 0; j < 4; j++) { int i = base + j; v[j] = (i < n) ? counts[i] : 0; s += v[j]; }
    sd[tid] = s; __syncthreads();
    for (int st = 1; st < 256; st <<= 1) {
        u32 t = (tid >= st) ? sd[tid - st] : 0;
        __syncthreads();
        sd[tid] += t;
        __syncthreads();
    }
    u32 run = bsum[blockIdx.x] + sd[tid] - s;
    #pragma unroll
    for (int j = 0; j < 4; j++) { int i = base + j; if (i < n) starts[i] = run; run += v[j]; }
}

// ==================== merged build: entry = in | k<<24 ====================
__global__ void buildF2_kernel(const int* __restrict__ i1, const int* __restrict__ o1,
                               const int* __restrict__ is, const int* __restrict__ os,
                               const u32* __restrict__ rowstart, u32* __restrict__ counts,
                               u32* __restrict__ listF) {
    int p = blockIdx.x * 256 + threadIdx.x;
    if (p >= 2 * NPAIRS) return;
    int bin; u32 w;
    if (p < NPAIRS) {
        bin = o1[p];
        w = (u32)i1[p] | ((u32)(p / R_PAIRS) << 24);
    } else {
        int q = p - NPAIRS;
        bin = N_OUT + os[q];
        w = (u32)is[q] | ((u32)(q / R_PAIRS) << 24);
    }
    u32 c = atomicSub(&counts[bin], 1u);
    listF[rowstart[bin] + c - 1u] = w;
}

// ==================== fused conv1+conv2: out-sorted spans + k-filter reduce ========
// 512 thr. Block = 32 out rows, contiguous span [lo,hiS) in listF.
// Stage: 16 thr/entry (float4 each), BN1+ReLU -> As bf16 [32][64]; meta k -> s_meta.
// Owner (row=tid>>4, sl=tid&15): k_own=sl>>1, ch slice (sl&1)*32; walks row span,
// filters k. z [32][512] bf16. GEMM 8 waves x 2 m-tiles.
__global__ __launch_bounds__(512) void fused12_kernel(
    const float* __restrict__ x, const bf16* __restrict__ Wf, const float* __restrict__ ss1,
    const u32* __restrict__ rowstart, const u32* __restrict__ listF,
    bf16* __restrict__ y1, bf16* __restrict__ y2b, float* __restrict__ sums2s)
{
    __shared__ bf16 z[BM * 512];      // 32 KB
    __shared__ bf16 As[CHUNK * 64];   // 4 KB
    __shared__ u32 s_meta[CHUNK];
    __shared__ float s_sc[64], s_sh[64];
    int tid = threadIdx.x, lane = tid & 63, wave = tid >> 6;
    int o0 = blockIdx.x * BM;
    int nrow = min(BM, N_OUT - o0);
    if (tid < 64) { s_sc[tid] = ss1[tid]; s_sh[tid] = ss1[64 + tid]; }

    int row = tid >> 4, sl = tid & 15;
    int kown = sl >> 1, ch0 = (sl & 1) * 32;
    u32 rs = 0, re = 0;
    if (row < nrow) { rs = rowstart[o0 + row]; re = rowstart[o0 + row + 1]; }
    u32 lo  = rowstart[o0];
    u32 hiS = rowstart[o0 + nrow];

    int esl  = tid >> 4;          // staged entry slot 0..31
    int cpos = (tid & 15) * 4;    // float offset within 64-float row
    u32 pw; float4 pv;

    auto issue = [&](u32 base) {
        u32 idx = base + esl;
        pw = (idx < hiS) ? listF[idx] : 0u;
        pv = *(const float4*)(x + (size_t)(pw & 0xFFFFFF) * 64 + cpos);
    };

    f32x4 a[8];
    #pragma unroll
    for (int g = 0; g < 8; g++) a[g] = (f32x4)(0.f);

    if (lo < hiS) issue(lo);
    for (u32 cb = lo; cb < hiS; cb += CHUNK) {
        int nE = (int)min((u32)CHUNK, hiS - cb);
        __syncthreads();              // As free; s_sc ready on first iter
        if (esl < nE) {
            float f[4] = {pv.x, pv.y, pv.z, pv.w};
            bf16x4 h;
            #pragma unroll
            for (int j = 0; j < 4; j++)
                h[j] = (bf16)fmaxf(f[j] * s_sc[cpos + j] + s_sh[cpos + j], 0.f);
            *(bf16x4*)((char*)As + ((esl * 128 + cpos * 2) ^ ((esl & 7) << 4))) = h;
            if ((tid & 15) == 0) s_meta[esl] = pw >> 24;
        }
        __syncthreads();              // As+meta ready
        if (cb + CHUNK < hiS) issue(cb + CHUNK);   // overlap next loads with reduce
        u32 pa = max(rs, cb), pb = min(re, cb + (u32)CHUNK);
        for (u32 p = pa; p < pb; p++) {
            int slot = (int)(p - cb);
            if ((int)s_meta[slot] != kown) continue;
            #pragma unroll
            for (int u = 0; u < 4; u++) {
                int bo = (slot * 128 + ch0 * 2 + u * 16) ^ ((slot & 7) << 4);
                int4 vi = *(const int4*)((const char*)As + bo);
                bf16x8 hv = *(bf16x8*)&vi;
                #pragma unroll
                for (int j = 0; j < 8; j++)
                    a[u * 2 + (j >> 2)][j & 3] += (float)hv[j];
            }
        }
    }
    __syncthreads();

    // z write (full coverage: 32 rows x 16 slices)
    {
        int colb = sl * 32;   // == (sl>>1)*64 + (sl&1)*32
        #pragma unroll
        for (int u = 0; u < 4; u++) {
            bf16x8 h;
            #pragma unroll
            for (int j = 0; j < 8; j++) h[j] = (bf16)a[u * 2 + (j >> 2)][j & 3];
            *(bf16x8*)((char*)z + zb(row, colb + u * 8)) = h;
        }
    }
    __syncthreads();

    // ---- GEMM [32 x 512] x [512 x 256], 8 waves: wave -> cat cols wave*32..+32 ----
    int l15 = lane & 15, kr0 = (lane >> 4) * 8;
    f32x4 acc[2][2];
    #pragma unroll
    for (int m = 0; m < 2; m++)
        #pragma unroll
        for (int nf = 0; nf < 2; nf++) acc[m][nf] = (f32x4)(0.f);

    for (int ks = 0; ks < 16; ks++) {
        int colb = ks * 32 + kr0;
        bf16x8 af0 = *(bf16x8*)((char*)z + zb(l15, colb));
        bf16x8 af1 = *(bf16x8*)((char*)z + zb(l15 + 16, colb));
        #pragma unroll
        for (int nf = 0; nf < 2; nf++) {
            bf16x8 bf = *(const bf16x8*)(Wf + ((size_t)(ks * 16 + wave * 2 + nf) * 64 + lane) * 8);
            acc[0][nf] = __builtin_amdgcn_mfma_f32_16x16x32_bf16(af0, bf, acc[0][nf], 0, 0, 0);
            acc[1][nf] = __builtin_amdgcn_mfma_f32_16x16x32_bf16(af1, bf, acc[1][nf], 0, 0, 0);
        }
    }
    __syncthreads();   // z reads done -> reuse as stage

    // stage bf16 [32 rows][256 cat cols] (16 KB)
    bf16* st = z;
    int rb = (lane >> 4) * 4;
    #pragma unroll
    for (int m = 0; m < 2; m++)
        #pragma unroll
        for (int nf = 0; nf < 2; nf++)
            #pragma unroll
            for (int j = 0; j < 4; j++)
                st[(m * 16 + rb + j) * 256 + wave * 32 + nf * 16 + l15] = (bf16)acc[m][nf][j];
    __syncthreads();

    // BN2 stats over y1 cols (0..127), striped atomics
    if (tid < 128) {
        float s = 0.f, q = 0.f;
        for (int r = 0; r < nrow; r++) { float v = (float)st[r * 256 + tid]; s += v; q += v * v; }
        int sb = (blockIdx.x & 63) * 256;
        atomicAdd(&sums2s[sb + tid], s);
        atomicAdd(&sums2s[sb + 128 + tid], q);
    }
    // output: 512 threads = 32 rows x 16 segs
    {
        int orow = tid >> 4, seg = tid & 15;
        if (orow < nrow) {
            const int4* src = (const int4*)(st + orow * 256 + seg * 16);
            int4 v0 = src[0], v1 = src[1];
            bf16* dst = (seg < 8) ? (y1  + (size_t)(o0 + orow) * 128 + seg * 16)
                                  : (y2b + (size_t)(o0 + orow) * 128 + (seg - 8) * 16);
            ((int4*)dst)[0] = v0; ((int4*)dst)[1] = v1;
        }
    }
}

// ==================== fused submanifold conv: out-sorted spans + k-filter ==========
// 512 thr. Stage: 16 thr/entry (int4=8 bf16 each), BN2+ReLU -> As [32][128]; meta k.
// Owner (row, sl): ch slice (sl&3)*32; accepts k with (k&3)==sl>>2, into aA (k<4)
// or aB (k>=4). Two K=512 GEMM halves share z.
__global__ __launch_bounds__(512) void fusedS_kernel(
    const bf16* __restrict__ y1, const bf16* __restrict__ Wf, const float* __restrict__ ss2,
    const u32* __restrict__ rowstart, const u32* __restrict__ listF,
    const bf16* __restrict__ y2b, float* __restrict__ out)
{
    __shared__ bf16 z[BM * 512];       // 32 KB
    __shared__ bf16 As[CHUNK * 128];   // 8 KB
    __shared__ u32 s_meta[CHUNK];
    __shared__ float s_sc[128], s_sh[128];
    int tid = threadIdx.x, lane = tid & 63, wave = tid >> 6;
    int o0 = blockIdx.x * BM;
    int nrow = min(BM, N_OUT - o0);
    if (tid < 128) { s_sc[tid] = ss2[tid]; s_sh[tid] = ss2[128 + tid]; }

    int row = tid >> 4, sl = tid & 15;
    int kq = sl >> 2, ch0 = (sl & 3) * 32;
    u32 rs = 0, re = 0;
    if (row < nrow) { rs = rowstart[o0 + row]; re = rowstart[o0 + row + 1]; }
    u32 lo  = rowstart[o0];
    u32 hiS = rowstart[o0 + nrow];

    int esl  = tid >> 4;          // staged entry slot 0..31
    int cpos = (tid & 15) * 8;    // bf16 offset within 128-ch row
    u32 pw; int4 pv;

    auto issue = [&](u32 base) {
        u32 idx = base + esl;
        pw = (idx < hiS) ? listF[idx] : 0u;
        pv = *(const int4*)(y1 + (size_t)(pw & 0xFFFFFF) * 128 + cpos);
    };

    f32x4 aA[8], aB[8];
    #pragma unroll
    for (int g = 0; g < 8; g++) { aA[g] = (f32x4)(0.f); aB[g] = (f32x4)(0.f); }

    if (lo < hiS) issue(lo);
    for (u32 cb = lo; cb < hiS; cb += CHUNK) {
        int nE = (int)min((u32)CHUNK, hiS - cb);
        __syncthreads();              // As free; s_sc ready on first iter
        if (esl < nE) {
            bf16x8 hv = *(bf16x8*)&pv;
            bf16x8 ho;
            #pragma unroll
            for (int j = 0; j < 8; j++)
                ho[j] = (bf16)fmaxf((float)hv[j] * s_sc[cpos + j] + s_sh[cpos + j], 0.f);
            *(bf16x8*)((char*)As + ((esl * 256 + cpos * 2) ^ ((esl & 7) << 4))) = ho;
            if ((tid & 15) == 0) s_meta[esl] = pw >> 24;
        }
        __syncthreads();              // As+meta ready
        if (cb + CHUNK < hiS) issue(cb + CHUNK);
        u32 pa = max(rs, cb), pb = min(re, cb + (u32)CHUNK);
        for (u32 p = pa; p < pb; p++) {
            int slot = (int)(p - cb);
            int k = (int)s_meta[slot];
            if ((k & 3) != kq) continue;
            f32x4 t[8];
            #pragma unroll
            for (int u = 0; u < 4; u++) {
                int bo = (slot * 256 + ch0 * 2 + u * 16) ^ ((slot & 7) << 4);
                int4 vi = *(const int4*)((const char*)As + bo);
                bf16x8 hv = *(bf16x8*)&vi;
                #pragma unroll
                for (int j = 0; j < 8; j++)
                    t[u * 2 + (j >> 2)][j & 3] = (float)hv[j];
            }
            if (k < 4) {
                #pragma unroll
                for (int g = 0; g < 8; g++) aA[g] += t[g];
            } else {
                #pragma unroll
                for (int g = 0; g < 8; g++) aB[g] += t[g];
            }
        }
    }

    int l15 = lane & 15, kr0 = (lane >> 4) * 8;
    f32x4 acc[2];
    acc[0] = (f32x4)(0.f); acc[1] = (f32x4)(0.f);
    int colb0 = sl * 32;   // == kq*128 + ch0

    #pragma unroll
    for (int h = 0; h < 2; h++) {
        __syncthreads();   // h=0: reduce done; h=1: GEMM h=0 z reads done
        {
            #pragma unroll
            for (int u = 0; u < 4; u++) {
                bf16x8 hv;
                #pragma unroll
                for (int j = 0; j < 8; j++)
                    hv[j] = (bf16)((h == 0 ? aA : aB)[u * 2 + (j >> 2)][j & 3]);
                *(bf16x8*)((char*)z + zb(row, colb0 + u * 8)) = hv;
            }
        }
        __syncthreads();

        for (int ks = 0; ks < 16; ks++) {
            int colb = ks * 32 + kr0;
            bf16x8 af0 = *(bf16x8*)((char*)z + zb(l15, colb));
            bf16x8 af1 = *(bf16x8*)((char*)z + zb(l15 + 16, colb));
            int fi = (h * 16 + ks) * 8 + wave;
            bf16x8 bf = *(const bf16x8*)(Wf + ((size_t)fi * 64 + lane) * 8);
            acc[0] = __builtin_amdgcn_mfma_f32_16x16x32_bf16(af0, bf, acc[0], 0, 0, 0);
            acc[1] = __builtin_amdgcn_mfma_f32_16x16x32_bf16(af1, bf, acc[1], 0, 0, 0);
        }
    }
    __syncthreads();

    // stage fp32 [32][128] (16 KB, inside z)
    float* zf = (float*)z;
    int rb = (lane >> 4) * 4;
    #pragma unroll
    for (int m = 0; m < 2; m++)
        #pragma unroll
        for (int j = 0; j < 4; j++)
            zf[(m * 16 + rb + j) * 128 + wave * 16 + l15] = acc[m][j];
    __syncthreads();

    {
        int orow = tid >> 4, seg = tid & 15;   // 8 floats each
        if (orow < nrow) {
            f32x4 s0 = *(f32x4*)&zf[orow * 128 + seg * 8];
            f32x4 s1 = *(f32x4*)&zf[orow * 128 + seg * 8 + 4];
            int4 yv = *(const int4*)(y2b + (size_t)(o0 + orow) * 128 + seg * 8);
            bf16x8 hy = *(bf16x8*)&yv;
            float4 w0 = make_float4(s0[0] + (float)hy[0], s0[1] + (float)hy[1],
                                    s0[2] + (float)hy[2], s0[3] + (float)hy[3]);
            float4 w1 = make_float4(s1[0] + (float)hy[4], s1[1] + (float)hy[5],
                                    s1[2] + (float)hy[6], s1[7 - 7] + 0.f);
            // (typo guard) recompute w1 correctly:
            w1 = make_float4(s1[0] + (float)hy[4], s1[1] + (float)hy[5],
                             s1[2] + (float)hy[6], s1[3] + (float)hy[7]);
            float* dst = out + (size_t)(o0 + orow) * 128 + seg * 8;
            *(float4*)dst = w0;
            *(float4*)(dst + 4) = w1;
        }
    }
}

// ==================== fallback (round-1 atomic path) ====================
__global__ __launch_bounds__(256) void conv12_atomic_kernel(
    const float* __restrict__ x,
    const float* __restrict__ W1, const float* __restrict__ W2,
    const int* __restrict__ in_idx, const int* __restrict__ out_idx,
    const float* __restrict__ ss1,
    float* __restrict__ y1, float* __restrict__ y2)
{
    int k    = blockIdx.y;
    int tid  = threadIdx.x;
    int wave = tid >> 6, lane = tid & 63;

    __shared__ bf16 As[64 * 64];
    __shared__ int  s_out[64];
    __shared__ float s_sc[64], s_sh[64];
    char* asb = (char*)As;

    if (tid < 64) { s_sc[tid] = ss1[tid]; s_sh[tid] = ss1[64 + tid]; }

    const float* Wk = ((wave & 2) ? W2 : W1) + (long)k * CIN * COUT;
    int nbase = (wave & 1) * 64;
    int l15 = lane & 15;
    int kr0 = (lane >> 4) * 8;

    bf16x8 bfrag[2][4];
    #pragma unroll
    for (int ks = 0; ks < 2; ks++)
        #pragma unroll
        for (int nf = 0; nf < 4; nf++) {
            const float* p = Wk + (long)(ks * 32 + kr0) * COUT + nbase + nf * 16 + l15;
            bf16x8 b;
            #pragma unroll
            for (int j = 0; j < 8; j++) b[j] = (bf16)p[(long)j * COUT];
            bfrag[ks][nf] = b;
        }

    const int* in_k  = in_idx  + k * R_PAIRS;
    const int* out_k = out_idx + k * R_PAIRS;
    float* ybase = (wave & 2) ? y2 : y1;

    int grow = tid >> 2;
    int gcol = (tid & 3) * 16;

    __syncthreads();

    for (int t = 0; t < OLD_TILES; t++) {
        int pair0 = blockIdx.x * (OLD_TILES * 64) + t * 64;
        {
            int p = pair0 + grow;
            bool valid = p < R_PAIRS;
            long src = valid ? (long)in_k[p] : 0;
            const float4* xr = (const float4*)(x + src * CIN + gcol);
            #pragma unroll
            for (int g = 0; g < 2; g++) {
                float4 va = make_float4(0, 0, 0, 0), vb = va;
                if (valid) { va = xr[g * 2]; vb = xr[g * 2 + 1]; }
                float f[8] = {va.x, va.y, va.z, va.w, vb.x, vb.y, vb.z, vb.w};
                bf16x8 h;
                #pragma unroll
                for (int j = 0; j < 8; j++) {
                    int c = gcol + g * 8 + j;
                    h[j] = (bf16)fmaxf(f[j] * s_sc[c] + s_sh[c], 0.f);
                }
                int boff = ((grow * 128) + (gcol + g * 8) * 2) ^ ((grow & 7) << 4);
                *(bf16x8*)(asb + boff) = h;
            }
        }
        if (tid < 64) {
            int p = pair0 + tid;
            s_out[tid] = (p < R_PAIRS) ? out_k[p] : -1;
        }
        __syncthreads();

        f32x4 acc[4][4];
        #pragma unroll
        for (int m = 0; m < 4; m++)
            #pragma unroll
            for (int n = 0; n < 4; n++) acc[m][n] = (f32x4)(0.f);

        #pragma unroll
        for (int ks = 0; ks < 2; ks++) {
            bf16x8 af[4];
            #pragma unroll
            for (int m = 0; m < 4; m++) {
                int rrow = m * 16 + l15;
                int boff = (rrow * 128 + (ks * 32 + kr0) * 2) ^ ((rrow & 7) << 4);
                af[m] = *(bf16x8*)(asb + boff);
            }
            #pragma unroll
            for (int m = 0; m < 4; m++)
                #pragma unroll
                for (int nf = 0; nf < 4; nf++)
                    acc[m][nf] = __builtin_amdgcn_mfma_f32_16x16x32_bf16(
                        af[m], bfrag[ks][nf], acc[m][nf], 0, 0, 0);
        }

        int rbase = (lane >> 4) * 4;
        #pragma unroll
        for (int m = 0; m < 4; m++)
            #pragma unroll
            for (int j = 0; j < 4; j++) {
                int o = s_out[m * 16 + rbase + j];
                if (o >= 0)
                    #pragma unroll
                    for (int nf = 0; nf < 4; nf++)
                        atomicAdd(&ybase[(long)o * COUT + nbase + nf * 16 + l15],
                                  acc[m][nf][j]);
            }
        __syncthreads();
    }
}

__global__ __launch_bounds__(256) void convs_atomic_kernel(
    const float* __restrict__ y1,
    const float* __restrict__ Ws,
    const int* __restrict__ in_idx, const int* __restrict__ out_idx,
    const float* __restrict__ ss2,
    float* __restrict__ out)
{
    int k    = blockIdx.y;
    int tid  = threadIdx.x;
    int wave = tid >> 6, lane = tid & 63;

    __shared__ bf16 As[64 * 128];
    __shared__ int  s_out[64];
    __shared__ float s_sc[128], s_sh[128];
    char* asb = (char*)As;

    if (tid < 128) { s_sc[tid] = ss2[tid]; s_sh[tid] = ss2[128 + tid]; }

    const float* Wk = Ws + (long)k * COUT * COUT;
    int nbase = wave * 32;
    int l15 = lane & 15;
    int kr0 = (lane >> 4) * 8;

    bf16x8 bfrag[4][2];
    #pragma unroll
    for (int ks = 0; ks < 4; ks++)
        #pragma unroll
        for (int nf = 0; nf < 2; nf++) {
            const float* p = Wk + (long)(ks * 32 + kr0) * COUT + nbase + nf * 16 + l15;
            bf16x8 b;
            #pragma unroll
            for (int j = 0; j < 8; j++) b[j] = (bf16)p[(long)j * COUT];
            bfrag[ks][nf] = b;
        }

    const int* in_k  = in_idx  + k * R_PAIRS;
    const int* out_k = out_idx + k * R_PAIRS;

    int grow = tid >> 2;
    int gcol = (tid & 3) * 32;

    __syncthreads();

    for (int t = 0; t < OLD_TILES; t++) {
        int pair0 = blockIdx.x * (OLD_TILES * 64) + t * 64;
        {
            int p = pair0 + grow;
            bool valid = p < R_PAIRS;
            long src = valid ? (long)in_k[p] : 0;
            const float4* yr = (const float4*)(y1 + src * COUT + gcol);
            #pragma unroll
            for (int g = 0; g < 4; g++) {
                float4 va = make_float4(0, 0, 0, 0), vb = va;
                if (valid) { va = yr[g * 2]; vb = yr[g * 2 + 1]; }
                float f[8] = {va.x, va.y, va.z, va.w, vb.x, vb.y, vb.z, vb.w};
                bf16x8 h;
                #pragma unroll
                for (int j = 0; j < 8; j++) {
                    int c = gcol + g * 8 + j;
                    h[j] = (bf16)fmaxf(f[j] * s_sc[c] + s_sh[c], 0.f);
                }
                int boff = (grow * 256 + (gcol + g * 8) * 2) ^ ((grow & 7) << 4);
                *(bf16x8*)(asb + boff) = h;
            }
        }
        if (tid < 64) {
            int p = pair0 + tid;
            s_out[tid] = (p < R_PAIRS) ? out_k[p] : -1;
        }
        __syncthreads();

        f32x4 acc[4][2];
        #pragma unroll
        for (int m = 0; m < 4; m++)
            #pragma unroll
            for (int n = 0; n < 2; n++) acc[m][n] = (f32x4)(0.f);

        #pragma unroll
        for (int ks = 0; ks < 4; ks++) {
            bf16x8 af[4];
            #pragma unroll
            for (int m = 0; m < 4; m++) {
                int rrow = m * 16 + l15;
                int boff = (rrow * 256 + (ks * 32 + kr0) * 2) ^ ((rrow & 7) << 4);
                af[m] = *(bf16x8*)(asb + boff);
            }
            #pragma unroll
            for (int m = 0; m < 4; m++)
                #pragma unroll
                for (int nf = 0; nf < 2; nf++)
                    acc[m][nf] = __builtin_amdgcn_mfma_f32_16x16x32_bf16(
                        af[m], bfrag[ks][nf], acc[m][nf], 0, 0, 0);
        }

        int rbase = (lane >> 4) * 4;
        #pragma unroll
        for (int m = 0; m < 4; m++)
            #pragma unroll
            for (int j = 0; j < 4; j++) {
                int o = s_out[m * 16 + rbase + j];
                if (o >= 0)
                    #pragma unroll
                    for (int nf = 0; nf < 2; nf++)
                        atomicAdd(&out[(long)o * COUT + nbase + nf * 16 + l15],
                                  acc[m][nf][j]);
            }
        __syncthreads();
    }
}

// ==================== host ====================
extern "C" void kernel_launch(void* const* d_in, const int* in_sizes, int n_in,
                              void* d_out, int out_size, void* d_ws, size_t ws_size,
                              hipStream_t stream) {
    const float* x       = (const float*)d_in[0];
    const float* gamma1  = (const float*)d_in[1];
    const float* beta1   = (const float*)d_in[2];
    const float* gamma2  = (const float*)d_in[3];
    const float* beta2   = (const float*)d_in[4];
    const float* W1      = (const float*)d_in[5];
    const float* Ws      = (const float*)d_in[6];
    const float* W2      = (const float*)d_in[7];
    const int*   in_idx1   = (const int*)d_in[8];
    const int*   out_idx1  = (const int*)d_in[9];
    const int*   in_idx_s  = (const int*)d_in[10];
    const int*   out_idx_s = (const int*)d_in[11];

    float* out = (float*)d_out;
    char*  ws  = (char*)d_ws;

    auto a256 = [](size_t v) { return (v + 255) & ~(size_t)255; };

    size_t off_y1      = 0;                                    // bf16 y1: 32 MB
    size_t off_y2b     = a256(off_y1 + 32000000);              // bf16 y2b: 32 MB
    size_t off_stats   = a256(off_y2b + 32000000);             // 4 KB (sums1,ss1,ss2)
    size_t off_s2s     = a256(off_stats + 4096);               // 64 KB
    size_t off_counts  = a256(off_s2s + 65536);                // 1 MB (250k bins)
    size_t off_rows    = a256(off_counts + 4ull * NB2);        // 1 MB + 4
    size_t off_bsum    = a256(off_rows + 4ull * (NB2 + 1));    // 1 KB
    size_t off_list    = a256(off_bsum + 1024);                // 4 MB (1M entries)
    size_t off_wf12    = a256(off_list + 4ull * 2 * NPAIRS);   // 256 KB
    size_t off_wfs     = a256(off_wf12 + 262144);              // 256 KB
    size_t need        = off_wfs + 262144;

    if (need > ws_size) {
        // -------- fallback: atomic path (needs only 64 MB + 4 KB) --------
        float* y1f   = (float*)ws;
        float* stats = y1f + (long)N_OUT * COUT;
        float* sums1 = stats;
        float* ss1   = stats + 128;
        float* sums2 = stats + 256;
        float* ss2   = stats + 512;

        hipMemsetAsync(d_out, 0, (size_t)N_OUT * COUT * 4, stream);
        hipMemsetAsync(d_ws,  0, (size_t)N_OUT * COUT * 4 + 768 * 4, stream);

        bn_stats_kernel<64><<<1024, 256, 0, stream>>>(x, N_IN, sums1);
        bn_finalize_kernel<64><<<1, 64, 0, stream>>>(sums1, gamma1, beta1, 1.f / N_IN, ss1);

        dim3 cgrid((R_PAIRS + OLD_TILES * 64 - 1) / (OLD_TILES * 64), K_OFF);
        conv12_atomic_kernel<<<cgrid, 256, 0, stream>>>(x, W1, W2, in_idx1, out_idx1, ss1, y1f, out);

        bn_stats_kernel<128><<<1024, 256, 0, stream>>>(y1f, N_OUT, sums2);
        bn_finalize_kernel<128><<<1, 128, 0, stream>>>(sums2, gamma2, beta2, 1.f / N_OUT, ss2);

        convs_atomic_kernel<<<cgrid, 256, 0, stream>>>(y1f, Ws, in_idx_s, out_idx_s, ss2, out);
        return;
    }

    bf16*  y1      = (bf16*)(ws + off_y1);
    bf16*  y2b     = (bf16*)(ws + off_y2b);
    float* sums1   = (float*)(ws + off_stats);    // [256]
    float* ss1     = sums1 + 256;                 // [256]
    float* ss2     = sums1 + 512;                 // [256]
    float* s2s     = (float*)(ws + off_s2s);      // [64][256]
    u32*   counts  = (u32*)(ws + off_counts);
    u32*   rowst   = (u32*)(ws + off_rows);
    u32*   bsum    = (u32*)(ws + off_bsum);
    u32*   list    = (u32*)(ws + off_list);
    bf16*  wf12    = (bf16*)(ws + off_wf12);
    bf16*  wfs     = (bf16*)(ws + off_wfs);

    int nblk = (N_OUT + BM - 1) / BM;    // 3907

    // ---- init ----
    hipMemsetAsync(ws + off_stats, 0, off_counts - off_stats, stream);   // stats + s2s
    hipMemsetAsync(counts, 0, 4ull * NB2, stream);

    // ---- merged rulebook sort (out-only, 250k bins) ----
    hist2_kernel<<<1024, 256, 0, stream>>>(out_idx1, out_idx_s, counts);
    scan1_kernel<<<NSB, 256, 0, stream>>>(counts, bsum, NB2);
    scan2_kernel<<<1, 256, 0, stream>>>(bsum, rowst, NSB, NB2);
    scan3_kernel<<<NSB, 256, 0, stream>>>(counts, bsum, rowst, NB2);
    buildF2_kernel<<<(2 * NPAIRS + 255) / 256, 256, 0, stream>>>(
        in_idx1, out_idx1, in_idx_s, out_idx_s, rowst, counts, list);

    // ---- BN1 stats (apply fused into fused12's stage); weight prepack ----
    bn_stats_kernel<64><<<1024, 256, 0, stream>>>(x, N_IN, sums1);
    bn_finalize_kernel<64><<<1, 64, 0, stream>>>(sums1, gamma1, beta1, 1.f / N_IN, ss1);
    pack12_kernel<<<512, 256, 0, stream>>>(W1, W2, wf12);
    packS_kernel<<<512, 256, 0, stream>>>(Ws, wfs);

    // ---- fused conv1+conv2 (BN1+ReLU fused into stage) ----
    fused12_kernel<<<nblk, 512, 0, stream>>>(x, wf12, ss1, rowst, list, y1, y2b, s2s);
    bn_finalize2_kernel<<<1, 128, 0, stream>>>(s2s, gamma2, beta2, ss2);

    // ---- fused submanifold conv (BN2+ReLU fused into stage, +y2b epilogue) ----
    fusedS_kernel<<<nblk, 512, 0, stream>>>(y1, wfs, ss2, rowst + N_OUT, list, y2b, out);
}

// Round 15
// 370.489 us; speedup vs baseline: 1.4581x; 1.4581x over previous
//
#include <hip/hip_runtime.h>

#define K_OFF   8
#define R_PAIRS 62500
#define NPAIRS  500000
#define N_IN    500000
#define N_OUT   125000
#define CIN     64
#define COUT    128
#define BN_EPS  1e-4f
#define NBINS_KC (N_OUT * K_OFF)     // 1,000,000
#define NB2     (2 * NBINS_KC)       // 2,000,000 (both rulebooks)
#define SCAN_E2 8192
#define NSB2    245                  // ceil(2e6 / 8192)
#define BM      32
#define CHUNK   32
#define OLD_TILES 8

typedef __bf16 bf16;
typedef __bf16 bf16x4 __attribute__((ext_vector_type(4)));
typedef __bf16 bf16x8 __attribute__((ext_vector_type(8)));
typedef float  f32x4  __attribute__((ext_vector_type(4)));
typedef unsigned int u32;

// bf16-z byte-offset swizzle: row-stride 1024B, inject row low bits into 16B-slot bits.
__device__ __forceinline__ int zb(int row, int col_bf16) {
    int byte = (row << 10) + (col_bf16 << 1);
    return byte ^ ((row & 7) << 4);
}

// ==================== BN statistics ====================
template<int C>
__global__ void bn_stats_kernel(const float* __restrict__ x, int n_rows,
                                float* __restrict__ sums /* [2C] */) {
    constexpr int CG = C / 4;
    int tid = blockIdx.x * blockDim.x + threadIdx.x;
    int nth = gridDim.x * blockDim.x;
    const float4* x4 = (const float4*)x;
    long n4 = (long)n_rows * CG;
    int cg = tid % CG;
    float s[4] = {0,0,0,0}, q[4] = {0,0,0,0};
    for (long i = tid; i < n4; i += nth) {
        float4 v = x4[i];
        float f[4] = {v.x, v.y, v.z, v.w};
        #pragma unroll
        for (int j = 0; j < 4; j++) { s[j] += f[j]; q[j] += f[j] * f[j]; }
    }
    __shared__ float acc[2 * C];
    for (int i = threadIdx.x; i < 2 * C; i += blockDim.x) acc[i] = 0.f;
    __syncthreads();
    #pragma unroll
    for (int j = 0; j < 4; j++) {
        atomicAdd(&acc[cg * 4 + j], s[j]);
        atomicAdd(&acc[C + cg * 4 + j], q[j]);
    }
    __syncthreads();
    for (int i = threadIdx.x; i < 2 * C; i += blockDim.x) atomicAdd(&sums[i], acc[i]);
}

template<int C>
__global__ void bn_finalize_kernel(const float* __restrict__ sums,
                                   const float* __restrict__ gamma,
                                   const float* __restrict__ beta,
                                   float inv_n, float* __restrict__ ss) {
    int c = threadIdx.x;
    if (c < C) {
        float m  = sums[c] * inv_n;
        float v  = sums[C + c] * inv_n - m * m;
        float sc = gamma[c] * rsqrtf(v + BN_EPS);
        ss[c]     = sc;
        ss[C + c] = beta[c] - m * sc;
    }
}

// BN2 finalize from 64 striped partial-sum copies
__global__ void bn_finalize2_kernel(const float* __restrict__ S /*[64][256]*/,
                                    const float* __restrict__ gamma,
                                    const float* __restrict__ beta,
                                    float* __restrict__ ss) {
    int c = threadIdx.x;   // 128
    float s = 0.f, q = 0.f;
    for (int st = 0; st < 64; st++) { s += S[st * 256 + c]; q += S[st * 256 + 128 + c]; }
    float m = s / (float)N_OUT;
    float v = q / (float)N_OUT - m * m;
    float sc = gamma[c] * rsqrtf(v + BN_EPS);
    ss[c] = sc; ss[128 + c] = beta[c] - m * sc;
}

// ==================== weight prepack (fragment order) ====================
__global__ void pack12_kernel(const float* __restrict__ W1, const float* __restrict__ W2,
                              bf16* __restrict__ Wf) {
    int idx = blockIdx.x * 256 + threadIdx.x;      // 131072
    int j = idx & 7;
    int lane = (idx >> 3) & 63;
    int fi = idx >> 9;            // 0..255
    int ks = fi >> 4, nfrag = fi & 15;
    int k512 = ks * 32 + (lane >> 4) * 8 + j;
    int koff = k512 >> 6, kc = k512 & 63;
    int c = nfrag * 16 + (lane & 15);
    const float* W = (c < 128) ? W1 : W2;
    Wf[idx] = (bf16)W[((long)koff * CIN + kc) * COUT + (c & 127)];
}

__global__ void packS_kernel(const float* __restrict__ Ws, bf16* __restrict__ Wf) {
    int idx = blockIdx.x * 256 + threadIdx.x;      // 131072
    int j = idx & 7;
    int lane = (idx >> 3) & 63;
    int fi = idx >> 9;            // 0..255
    int ksg = fi >> 3, nfrag = fi & 7;
    int k1024 = ksg * 32 + (lane >> 4) * 8 + j;
    int koff = k1024 >> 7, kc = k1024 & 127;
    int c = nfrag * 16 + (lane & 15);
    Wf[idx] = (bf16)Ws[((long)koff * COUT + kc) * COUT + c];
}

// ==================== merged hist over both rulebooks (2M bins) ====================
__global__ void hist2_kernel(const int* __restrict__ o1, const int* __restrict__ os,
                             u32* __restrict__ counts) {
    int p = blockIdx.x * blockDim.x + threadIdx.x;
    int stride = gridDim.x * blockDim.x;
    for (; p < 2 * NPAIRS; p += stride) {
        int bin;
        if (p < NPAIRS) bin = o1[p] * K_OFF + p / R_PAIRS;
        else { int q = p - NPAIRS; bin = NBINS_KC + os[q] * K_OFF + q / R_PAIRS; }
        atomicAdd(&counts[bin], 1u);
    }
}

// ==================== 3-level scan, 8192 elems/block ====================
__global__ void scan1_kernel(const u32* __restrict__ counts, u32* __restrict__ bsum, int n) {
    __shared__ u32 sd[256];
    int tid = threadIdx.x;
    int base = blockIdx.x * SCAN_E2 + tid * 32;
    u32 s = 0;
    #pragma unroll
    for (int j = 0; j < 32; j++) { int i = base + j; if (i < n) s += counts[i]; }
    sd[tid] = s; __syncthreads();
    for (int st = 128; st > 0; st >>= 1) { if (tid < st) sd[tid] += sd[tid + st]; __syncthreads(); }
    if (tid == 0) bsum[blockIdx.x] = sd[0];
}

__global__ void scan2_kernel(u32* __restrict__ bsum, u32* __restrict__ starts, int nb, int n) {
    __shared__ u32 sd[256];
    int tid = threadIdx.x;
    u32 v = (tid < nb) ? bsum[tid] : 0;
    sd[tid] = v; __syncthreads();
    for (int st = 1; st < 256; st <<= 1) {
        u32 t = (tid >= st) ? sd[tid - st] : 0;
        __syncthreads();
        sd[tid] += t;
        __syncthreads();
    }
    if (tid < nb) bsum[tid] = sd[tid] - v;     // exclusive
    if (tid == 255) starts[n] = sd[255];       // total
}

__global__ void scan3_kernel(const u32* __restrict__ counts, const u32* __restrict__ bsum,
                             u32* __restrict__ starts, int n) {
    __shared__ u32 sd[256];
    int tid = threadIdx.x;
    int base = blockIdx.x * SCAN_E2 + tid * 32;
    u32 v[32]; u32 s = 0;
    #pragma unroll
    for (int j = 0; j < 32; j++) { int i = base + j; v[j] = (i < n) ? counts[i] : 0; s += v[j]; }
    sd[tid] = s; __syncthreads();
    for (int st = 1; st < 256; st <<= 1) {
        u32 t = (tid >= st) ? sd[tid - st] : 0;
        __syncthreads();
        sd[tid] += t;
        __syncthreads();
    }
    u32 run = bsum[blockIdx.x] + sd[tid] - s;
    #pragma unroll
    for (int j = 0; j < 32; j++) { int i = base + j; if (i < n) starts[i] = run; run += v[j]; }
}

// ==================== merged build (cursor = counts, atomicSub) ====================
__global__ void buildF2_kernel(const int* __restrict__ i1, const int* __restrict__ o1,
                               const int* __restrict__ is, const int* __restrict__ os,
                               const u32* __restrict__ kstart, u32* __restrict__ counts,
                               u32* __restrict__ listF) {
    int p = blockIdx.x * 256 + threadIdx.x;
    if (p >= 2 * NPAIRS) return;
    int bin, in;
    if (p < NPAIRS) { bin = o1[p] * K_OFF + p / R_PAIRS; in = i1[p]; }
    else { int q = p - NPAIRS; bin = NBINS_KC + os[q] * K_OFF + q / R_PAIRS; in = is[q]; }
    u32 c = atomicSub(&counts[bin], 1u);
    listF[kstart[bin] + c - 1u] = (u32)in;
}

// ==================== fused conv1+conv2: (out,k)-sorted + deep prefetch ============
// 512 thr. CHUNK=32: stage = 1 round (16 thr/entry, float4 each).
// Prefetch: listF word held 2 chunks ahead; x data 1 chunk ahead.
// Owner (row=tid>>4, sl=tid&15): k=sl>>1, ch slice (sl&1)*32. z [32][512] bf16.
__global__ __launch_bounds__(512) void fused12_kernel(
    const float* __restrict__ x, const bf16* __restrict__ Wf, const float* __restrict__ ss1,
    const u32* __restrict__ kstart, const u32* __restrict__ listF,
    bf16* __restrict__ y1, bf16* __restrict__ y2b, float* __restrict__ sums2s)
{
    __shared__ bf16 z[BM * 512];      // 32 KB
    __shared__ bf16 As[CHUNK * 64];   // 4 KB
    __shared__ float s_sc[64], s_sh[64];
    int tid = threadIdx.x, lane = tid & 63, wave = tid >> 6;
    int o0 = blockIdx.x * BM;
    int nrow = min(BM, N_OUT - o0);
    if (tid < 64) { s_sc[tid] = ss1[tid]; s_sh[tid] = ss1[64 + tid]; }

    int row = tid >> 4, sl = tid & 15;
    int ch0 = (sl & 1) * 32;
    u32 sA = 0, eA = 0;
    if (row < nrow) {
        size_t bin = (size_t)(o0 + row) * K_OFF + (sl >> 1);
        sA = kstart[bin]; eA = kstart[bin + 1];
    }
    u32 lo  = kstart[(size_t)o0 * K_OFF];
    u32 hiS = kstart[(size_t)(o0 + nrow) * K_OFF];

    int esl  = tid >> 4;          // staged entry slot 0..31
    int cpos = (tid & 15) * 4;    // float offset within 64-float row
    u32 pwN; float4 pv;

    // prologue: chunk0 data + chunk1 listF word
    {
        u32 i0 = lo + esl;
        u32 w = (i0 < hiS) ? listF[i0] : 0u;
        pv = *(const float4*)(x + (size_t)w * 64 + cpos);
        u32 i1 = lo + CHUNK + esl;
        pwN = (i1 < hiS) ? listF[i1] : 0u;
    }

    f32x4 a[8];
    #pragma unroll
    for (int g = 0; g < 8; g++) a[g] = (f32x4)(0.f);

    for (u32 cb = lo; cb < hiS; cb += CHUNK) {
        int nE = (int)min((u32)CHUNK, hiS - cb);
        __syncthreads();              // As free; s_sc ready on first iter
        if (esl < nE) {
            float f[4] = {pv.x, pv.y, pv.z, pv.w};
            bf16x4 h;
            #pragma unroll
            for (int j = 0; j < 4; j++)
                h[j] = (bf16)fmaxf(f[j] * s_sc[cpos + j] + s_sh[cpos + j], 0.f);
            *(bf16x4*)((char*)As + ((esl * 128 + cpos * 2) ^ ((esl & 7) << 4))) = h;
        }
        // issue chunk c+1 data and chunk c+2 listF (overlap with barrier+reduce)
        float4 pvN = *(const float4*)(x + (size_t)(pwN & 0xFFFFFFu) * 64 + cpos);
        u32 i2 = cb + 2 * CHUNK + esl;
        u32 pwNN = (i2 < hiS) ? listF[i2] : 0u;
        __syncthreads();              // As ready
        u32 pa = max(sA, cb), pb = min(eA, cb + (u32)CHUNK);
        for (u32 p = pa; p < pb; p++) {
            int slot = (int)(p - cb);
            #pragma unroll
            for (int u = 0; u < 4; u++) {
                int bo = (slot * 128 + ch0 * 2 + u * 16) ^ ((slot & 7) << 4);
                int4 vi = *(const int4*)((const char*)As + bo);
                bf16x8 hv = *(bf16x8*)&vi;
                #pragma unroll
                for (int j = 0; j < 8; j++)
                    a[u * 2 + (j >> 2)][j & 3] += (float)hv[j];
            }
        }
        pv = pvN; pwN = pwNN;
    }
    __syncthreads();

    // z write (full coverage: 32 rows x 16 slices)
    {
        int colb = sl * 32;   // == (sl>>1)*64 + (sl&1)*32
        #pragma unroll
        for (int u = 0; u < 4; u++) {
            bf16x8 h;
            #pragma unroll
            for (int j = 0; j < 8; j++) h[j] = (bf16)a[u * 2 + (j >> 2)][j & 3];
            *(bf16x8*)((char*)z + zb(row, colb + u * 8)) = h;
        }
    }
    __syncthreads();

    // ---- GEMM [32 x 512] x [512 x 256], 8 waves: wave -> cat cols wave*32..+32 ----
    int l15 = lane & 15, kr0 = (lane >> 4) * 8;
    f32x4 acc[2][2];
    #pragma unroll
    for (int m = 0; m < 2; m++)
        #pragma unroll
        for (int nf = 0; nf < 2; nf++) acc[m][nf] = (f32x4)(0.f);

    for (int ks = 0; ks < 16; ks++) {
        int colb = ks * 32 + kr0;
        bf16x8 af0 = *(bf16x8*)((char*)z + zb(l15, colb));
        bf16x8 af1 = *(bf16x8*)((char*)z + zb(l15 + 16, colb));
        #pragma unroll
        for (int nf = 0; nf < 2; nf++) {
            bf16x8 bf = *(const bf16x8*)(Wf + ((size_t)(ks * 16 + wave * 2 + nf) * 64 + lane) * 8);
            acc[0][nf] = __builtin_amdgcn_mfma_f32_16x16x32_bf16(af0, bf, acc[0][nf], 0, 0, 0);
            acc[1][nf] = __builtin_amdgcn_mfma_f32_16x16x32_bf16(af1, bf, acc[1][nf], 0, 0, 0);
        }
    }
    __syncthreads();   // z reads done -> reuse as stage

    // stage bf16 [32 rows][256 cat cols] (16 KB)
    bf16* st = z;
    int rb = (lane >> 4) * 4;
    #pragma unroll
    for (int m = 0; m < 2; m++)
        #pragma unroll
        for (int nf = 0; nf < 2; nf++)
            #pragma unroll
            for (int j = 0; j < 4; j++)
                st[(m * 16 + rb + j) * 256 + wave * 32 + nf * 16 + l15] = (bf16)acc[m][nf][j];
    __syncthreads();

    // BN2 stats over y1 cols (0..127), striped atomics
    if (tid < 128) {
        float s = 0.f, q = 0.f;
        for (int r = 0; r < nrow; r++) { float v = (float)st[r * 256 + tid]; s += v; q += v * v; }
        int sb = (blockIdx.x & 63) * 256;
        atomicAdd(&sums2s[sb + tid], s);
        atomicAdd(&sums2s[sb + 128 + tid], q);
    }
    // output: 512 threads = 32 rows x 16 segs
    {
        int orow = tid >> 4, seg = tid & 15;
        if (orow < nrow) {
            const int4* src = (const int4*)(st + orow * 256 + seg * 16);
            int4 v0 = src[0], v1 = src[1];
            bf16* dst = (seg < 8) ? (y1  + (size_t)(o0 + orow) * 128 + seg * 16)
                                  : (y2b + (size_t)(o0 + orow) * 128 + (seg - 8) * 16);
            ((int4*)dst)[0] = v0; ((int4*)dst)[1] = v1;
        }
    }
}

// ==================== fused submanifold: dbuf stage (1 barrier/chunk) + prefetch ===
// 512 thr. CHUNK=32 (16 thr/entry, int4=8 bf16 each). Owner (row, sl): ch slice
// (sl&3)*32, bins k=sl>>2 (aA) and 4+(sl>>2) (aB), both reduced per chunk.
__global__ __launch_bounds__(512) void fusedS_kernel(
    const bf16* __restrict__ y1, const bf16* __restrict__ Wf, const float* __restrict__ ss2,
    const u32* __restrict__ kstart, const u32* __restrict__ listF,
    const bf16* __restrict__ y2b, float* __restrict__ out)
{
    __shared__ bf16 z[BM * 512];          // 32 KB
    __shared__ bf16 As[2][CHUNK * 128];   // 2 x 8 KB
    __shared__ float s_sc[128], s_sh[128];
    int tid = threadIdx.x, lane = tid & 63, wave = tid >> 6;
    int o0 = blockIdx.x * BM;
    int nrow = min(BM, N_OUT - o0);
    if (tid < 128) { s_sc[tid] = ss2[tid]; s_sh[tid] = ss2[128 + tid]; }

    int row = tid >> 4, sl = tid & 15;
    int kq = sl >> 2, ch0 = (sl & 3) * 32;
    u32 sA = 0, eA = 0, sB = 0, eB = 0;
    if (row < nrow) {
        size_t binb = (size_t)(o0 + row) * K_OFF;
        sA = kstart[binb + kq];     eA = kstart[binb + kq + 1];
        sB = kstart[binb + 4 + kq]; eB = kstart[binb + 4 + kq + 1];
    }
    u32 lo  = kstart[(size_t)o0 * K_OFF];
    u32 hiS = kstart[(size_t)(o0 + nrow) * K_OFF];

    int esl  = tid >> 4;          // staged entry slot 0..31
    int cpos = (tid & 15) * 8;    // bf16 offset within 128-ch row
    u32 pwN; int4 pv;

    // prologue: chunk0 data + chunk1 listF word
    {
        u32 i0 = lo + esl;
        u32 w = (i0 < hiS) ? listF[i0] : 0u;
        pv = *(const int4*)(y1 + (size_t)w * 128 + cpos);
        u32 i1 = lo + CHUNK + esl;
        pwN = (i1 < hiS) ? listF[i1] : 0u;
    }

    f32x4 aA[8], aB[8];
    #pragma unroll
    for (int g = 0; g < 8; g++) { aA[g] = (f32x4)(0.f); aB[g] = (f32x4)(0.f); }

    __syncthreads();   // s_sc/s_sh ready before first stage-convert

    int ci = 0;
    for (u32 cb = lo; cb < hiS; cb += CHUNK, ci ^= 1) {
        int nE = (int)min((u32)CHUNK, hiS - cb);
        if (esl < nE) {
            bf16x8 hv = *(bf16x8*)&pv;
            bf16x8 ho;
            #pragma unroll
            for (int j = 0; j < 8; j++)
                ho[j] = (bf16)fmaxf((float)hv[j] * s_sc[cpos + j] + s_sh[cpos + j], 0.f);
            *(bf16x8*)((char*)As[ci] + ((esl * 256 + cpos * 2) ^ ((esl & 7) << 4))) = ho;
        }
        // issue chunk c+1 data and chunk c+2 listF (overlap with barrier+reduce)
        int4 pvN = *(const int4*)(y1 + (size_t)(pwN & 0xFFFFFFu) * 128 + cpos);
        u32 i2 = cb + 2 * CHUNK + esl;
        u32 pwNN = (i2 < hiS) ? listF[i2] : 0u;
        __syncthreads();              // As[ci] ready (prev readers of As[ci] done pre-last-barrier)
        u32 pa = max(sA, cb), pb = min(eA, cb + (u32)CHUNK);
        for (u32 p = pa; p < pb; p++) {
            int slot = (int)(p - cb);
            #pragma unroll
            for (int u = 0; u < 4; u++) {
                int bo = (slot * 256 + ch0 * 2 + u * 16) ^ ((slot & 7) << 4);
                int4 vi = *(const int4*)((const char*)As[ci] + bo);
                bf16x8 hv = *(bf16x8*)&vi;
                #pragma unroll
                for (int j = 0; j < 8; j++)
                    aA[u * 2 + (j >> 2)][j & 3] += (float)hv[j];
            }
        }
        pa = max(sB, cb); pb = min(eB, cb + (u32)CHUNK);
        for (u32 p = pa; p < pb; p++) {
            int slot = (int)(p - cb);
            #pragma unroll
            for (int u = 0; u < 4; u++) {
                int bo = (slot * 256 + ch0 * 2 + u * 16) ^ ((slot & 7) << 4);
                int4 vi = *(const int4*)((const char*)As[ci] + bo);
                bf16x8 hv = *(bf16x8*)&vi;
                #pragma unroll
                for (int j = 0; j < 8; j++)
                    aB[u * 2 + (j >> 2)][j & 3] += (float)hv[j];
            }
        }
        pv = pvN; pwN = pwNN;
    }

    int l15 = lane & 15, kr0 = (lane >> 4) * 8;
    f32x4 acc[2];
    acc[0] = (f32x4)(0.f); acc[1] = (f32x4)(0.f);
    int colb0 = sl * 32;   // == kq*128 + ch0

    #pragma unroll
    for (int h = 0; h < 2; h++) {
        __syncthreads();   // h=0: all reduces done; h=1: GEMM h=0 z reads done
        {
            #pragma unroll
            for (int u = 0; u < 4; u++) {
                bf16x8 hv;
                #pragma unroll
                for (int j = 0; j < 8; j++)
                    hv[j] = (bf16)((h == 0 ? aA : aB)[u * 2 + (j >> 2)][j & 3]);
                *(bf16x8*)((char*)z + zb(row, colb0 + u * 8)) = hv;
            }
        }
        __syncthreads();

        for (int ks = 0; ks < 16; ks++) {
            int colb = ks * 32 + kr0;
            bf16x8 af0 = *(bf16x8*)((char*)z + zb(l15, colb));
            bf16x8 af1 = *(bf16x8*)((char*)z + zb(l15 + 16, colb));
            int fi = (h * 16 + ks) * 8 + wave;
            bf16x8 bf = *(const bf16x8*)(Wf + ((size_t)fi * 64 + lane) * 8);
            acc[0] = __builtin_amdgcn_mfma_f32_16x16x32_bf16(af0, bf, acc[0], 0, 0, 0);
            acc[1] = __builtin_amdgcn_mfma_f32_16x16x32_bf16(af1, bf, acc[1], 0, 0, 0);
        }
    }
    __syncthreads();

    // stage fp32 [32][128] (16 KB, inside z)
    float* zf = (float*)z;
    int rb = (lane >> 4) * 4;
    #pragma unroll
    for (int m = 0; m < 2; m++)
        #pragma unroll
        for (int j = 0; j < 4; j++)
            zf[(m * 16 + rb + j) * 128 + wave * 16 + l15] = acc[m][j];
    __syncthreads();

    {
        int orow = tid >> 4, seg = tid & 15;   // 8 floats each
        if (orow < nrow) {
            f32x4 s0 = *(f32x4*)&zf[orow * 128 + seg * 8];
            f32x4 s1 = *(f32x4*)&zf[orow * 128 + seg * 8 + 4];
            int4 yv = *(const int4*)(y2b + (size_t)(o0 + orow) * 128 + seg * 8);
            bf16x8 hy = *(bf16x8*)&yv;
            float4 w0 = make_float4(s0[0] + (float)hy[0], s0[1] + (float)hy[1],
                                    s0[2] + (float)hy[2], s0[3] + (float)hy[3]);
            float4 w1 = make_float4(s1[0] + (float)hy[4], s1[1] + (float)hy[5],
                                    s1[2] + (float)hy[6], s1[3] + (float)hy[7]);
            float* dst = out + (size_t)(o0 + orow) * 128 + seg * 8;
            *(float4*)dst = w0;
            *(float4*)(dst + 4) = w1;
        }
    }
}

// ==================== fallback (round-1 atomic path) ====================
__global__ __launch_bounds__(256) void conv12_atomic_kernel(
    const float* __restrict__ x,
    const float* __restrict__ W1, const float* __restrict__ W2,
    const int* __restrict__ in_idx, const int* __restrict__ out_idx,
    const float* __restrict__ ss1,
    float* __restrict__ y1, float* __restrict__ y2)
{
    int k    = blockIdx.y;
    int tid  = threadIdx.x;
    int wave = tid >> 6, lane = tid & 63;

    __shared__ bf16 As[64 * 64];
    __shared__ int  s_out[64];
    __shared__ float s_sc[64], s_sh[64];
    char* asb = (char*)As;

    if (tid < 64) { s_sc[tid] = ss1[tid]; s_sh[tid] = ss1[64 + tid]; }

    const float* Wk = ((wave & 2) ? W2 : W1) + (long)k * CIN * COUT;
    int nbase = (wave & 1) * 64;
    int l15 = lane & 15;
    int kr0 = (lane >> 4) * 8;

    bf16x8 bfrag[2][4];
    #pragma unroll
    for (int ks = 0; ks < 2; ks++)
        #pragma unroll
        for (int nf = 0; nf < 4; nf++) {
            const float* p = Wk + (long)(ks * 32 + kr0) * COUT + nbase + nf * 16 + l15;
            bf16x8 b;
            #pragma unroll
            for (int j = 0; j < 8; j++) b[j] = (bf16)p[(long)j * COUT];
            bfrag[ks][nf] = b;
        }

    const int* in_k  = in_idx  + k * R_PAIRS;
    const int* out_k = out_idx + k * R_PAIRS;
    float* ybase = (wave & 2) ? y2 : y1;

    int grow = tid >> 2;
    int gcol = (tid & 3) * 16;

    __syncthreads();

    for (int t = 0; t < OLD_TILES; t++) {
        int pair0 = blockIdx.x * (OLD_TILES * 64) + t * 64;
        {
            int p = pair0 + grow;
            bool valid = p < R_PAIRS;
            long src = valid ? (long)in_k[p] : 0;
            const float4* xr = (const float4*)(x + src * CIN + gcol);
            #pragma unroll
            for (int g = 0; g < 2; g++) {
                float4 va = make_float4(0, 0, 0, 0), vb = va;
                if (valid) { va = xr[g * 2]; vb = xr[g * 2 + 1]; }
                float f[8] = {va.x, va.y, va.z, va.w, vb.x, vb.y, vb.z, vb.w};
                bf16x8 h;
                #pragma unroll
                for (int j = 0; j < 8; j++) {
                    int c = gcol + g * 8 + j;
                    h[j] = (bf16)fmaxf(f[j] * s_sc[c] + s_sh[c], 0.f);
                }
                int boff = ((grow * 128) + (gcol + g * 8) * 2) ^ ((grow & 7) << 4);
                *(bf16x8*)(asb + boff) = h;
            }
        }
        if (tid < 64) {
            int p = pair0 + tid;
            s_out[tid] = (p < R_PAIRS) ? out_k[p] : -1;
        }
        __syncthreads();

        f32x4 acc[4][4];
        #pragma unroll
        for (int m = 0; m < 4; m++)
            #pragma unroll
            for (int n = 0; n < 4; n++) acc[m][n] = (f32x4)(0.f);

        #pragma unroll
        for (int ks = 0; ks < 2; ks++) {
            bf16x8 af[4];
            #pragma unroll
            for (int m = 0; m < 4; m++) {
                int rrow = m * 16 + l15;
                int boff = (rrow * 128 + (ks * 32 + kr0) * 2) ^ ((rrow & 7) << 4);
                af[m] = *(bf16x8*)(asb + boff);
            }
            #pragma unroll
            for (int m = 0; m < 4; m++)
                #pragma unroll
                for (int nf = 0; nf < 4; nf++)
                    acc[m][nf] = __builtin_amdgcn_mfma_f32_16x16x32_bf16(
                        af[m], bfrag[ks][nf], acc[m][nf], 0, 0, 0);
        }

        int rbase = (lane >> 4) * 4;
        #pragma unroll
        for (int m = 0; m < 4; m++)
            #pragma unroll
            for (int j = 0; j < 4; j++) {
                int o = s_out[m * 16 + rbase + j];
                if (o >= 0)
                    #pragma unroll
                    for (int nf = 0; nf < 4; nf++)
                        atomicAdd(&ybase[(long)o * COUT + nbase + nf * 16 + l15],
                                  acc[m][nf][j]);
            }
        __syncthreads();
    }
}

__global__ __launch_bounds__(256) void convs_atomic_kernel(
    const float* __restrict__ y1,
    const float* __restrict__ Ws,
    const int* __restrict__ in_idx, const int* __restrict__ out_idx,
    const float* __restrict__ ss2,
    float* __restrict__ out)
{
    int k    = blockIdx.y;
    int tid  = threadIdx.x;
    int wave = tid >> 6, lane = tid & 63;

    __shared__ bf16 As[64 * 128];
    __shared__ int  s_out[64];
    __shared__ float s_sc[128], s_sh[128];
    char* asb = (char*)As;

    if (tid < 128) { s_sc[tid] = ss2[tid]; s_sh[tid] = ss2[128 + tid]; }

    const float* Wk = Ws + (long)k * COUT * COUT;
    int nbase = wave * 32;
    int l15 = lane & 15;
    int kr0 = (lane >> 4) * 8;

    bf16x8 bfrag[4][2];
    #pragma unroll
    for (int ks = 0; ks < 4; ks++)
        #pragma unroll
        for (int nf = 0; nf < 2; nf++) {
            const float* p = Wk + (long)(ks * 32 + kr0) * COUT + nbase + nf * 16 + l15;
            bf16x8 b;
            #pragma unroll
            for (int j = 0; j < 8; j++) b[j] = (bf16)p[(long)j * COUT];
            bfrag[ks][nf] = b;
        }

    const int* in_k  = in_idx  + k * R_PAIRS;
    const int* out_k = out_idx + k * R_PAIRS;

    int grow = tid >> 2;
    int gcol = (tid & 3) * 32;

    __syncthreads();

    for (int t = 0; t < OLD_TILES; t++) {
        int pair0 = blockIdx.x * (OLD_TILES * 64) + t * 64;
        {
            int p = pair0 + grow;
            bool valid = p < R_PAIRS;
            long src = valid ? (long)in_k[p] : 0;
            const float4* yr = (const float4*)(y1 + src * COUT + gcol);
            #pragma unroll
            for (int g = 0; g < 4; g++) {
                float4 va = make_float4(0, 0, 0, 0), vb = va;
                if (valid) { va = yr[g * 2]; vb = yr[g * 2 + 1]; }
                float f[8] = {va.x, va.y, va.z, va.w, vb.x, vb.y, vb.z, vb.w};
                bf16x8 h;
                #pragma unroll
                for (int j = 0; j < 8; j++) {
                    int c = gcol + g * 8 + j;
                    h[j] = (bf16)fmaxf(f[j] * s_sc[c] + s_sh[c], 0.f);
                }
                int boff = (grow * 256 + (gcol + g * 8) * 2) ^ ((grow & 7) << 4);
                *(bf16x8*)(asb + boff) = h;
            }
        }
        if (tid < 64) {
            int p = pair0 + tid;
            s_out[tid] = (p < R_PAIRS) ? out_k[p] : -1;
        }
        __syncthreads();

        f32x4 acc[4][2];
        #pragma unroll
        for (int m = 0; m < 4; m++)
            #pragma unroll
            for (int n = 0; n < 2; n++) acc[m][n] = (f32x4)(0.f);

        #pragma unroll
        for (int ks = 0; ks < 4; ks++) {
            bf16x8 af[4];
            #pragma unroll
            for (int m = 0; m < 4; m++) {
                int rrow = m * 16 + l15;
                int boff = (rrow * 256 + (ks * 32 + kr0) * 2) ^ ((rrow & 7) << 4);
                af[m] = *(bf16x8*)(asb + boff);
            }
            #pragma unroll
            for (int m = 0; m < 4; m++)
                #pragma unroll
                for (int nf = 0; nf < 2; nf++)
                    acc[m][nf] = __builtin_amdgcn_mfma_f32_16x16x32_bf16(
                        af[m], bfrag[ks][nf], acc[m][nf], 0, 0, 0);
        }

        int rbase = (lane >> 4) * 4;
        #pragma unroll
        for (int m = 0; m < 4; m++)
            #pragma unroll
            for (int j = 0; j < 4; j++) {
                int o = s_out[m * 16 + rbase + j];
                if (o >= 0)
                    #pragma unroll
                    for (int nf = 0; nf < 2; nf++)
                        atomicAdd(&out[(long)o * COUT + nbase + nf * 16 + l15],
                                  acc[m][nf][j]);
            }
        __syncthreads();
    }
}

// ==================== host ====================
extern "C" void kernel_launch(void* const* d_in, const int* in_sizes, int n_in,
                              void* d_out, int out_size, void* d_ws, size_t ws_size,
                              hipStream_t stream) {
    const float* x       = (const float*)d_in[0];
    const float* gamma1  = (const float*)d_in[1];
    const float* beta1   = (const float*)d_in[2];
    const float* gamma2  = (const float*)d_in[3];
    const float* beta2   = (const float*)d_in[4];
    const float* W1      = (const float*)d_in[5];
    const float* Ws      = (const float*)d_in[6];
    const float* W2      = (const float*)d_in[7];
    const int*   in_idx1   = (const int*)d_in[8];
    const int*   out_idx1  = (const int*)d_in[9];
    const int*   in_idx_s  = (const int*)d_in[10];
    const int*   out_idx_s = (const int*)d_in[11];

    float* out = (float*)d_out;
    char*  ws  = (char*)d_ws;

    auto a256 = [](size_t v) { return (v + 255) & ~(size_t)255; };

    size_t off_y1      = 0;                                    // bf16 y1: 32 MB
    size_t off_y2b     = a256(off_y1 + 32000000);              // bf16 y2b: 32 MB
    size_t off_stats   = a256(off_y2b + 32000000);             // 4 KB (sums1,ss1,ss2)
    size_t off_s2s     = a256(off_stats + 4096);               // 64 KB
    size_t off_counts  = a256(off_s2s + 65536);                // 8 MB (2M bins)
    size_t off_kstart  = a256(off_counts + 4ull * NB2);        // 8 MB + 4
    size_t off_bsum    = a256(off_kstart + 4ull * (NB2 + 1));  // 1 KB
    size_t off_list    = a256(off_bsum + 1024);                // 4 MB (1M entries)
    size_t off_wf12    = a256(off_list + 4ull * 2 * NPAIRS);   // 256 KB
    size_t off_wfs     = a256(off_wf12 + 262144);              // 256 KB
    size_t need        = off_wfs + 262144;

    if (need > ws_size) {
        // -------- fallback: atomic path (needs only 64 MB + 4 KB) --------
        float* y1f   = (float*)ws;
        float* stats = y1f + (long)N_OUT * COUT;
        float* sums1 = stats;
        float* ss1   = stats + 128;
        float* sums2 = stats + 256;
        float* ss2   = stats + 512;

        hipMemsetAsync(d_out, 0, (size_t)N_OUT * COUT * 4, stream);
        hipMemsetAsync(d_ws,  0, (size_t)N_OUT * COUT * 4 + 768 * 4, stream);

        bn_stats_kernel<64><<<1024, 256, 0, stream>>>(x, N_IN, sums1);
        bn_finalize_kernel<64><<<1, 64, 0, stream>>>(sums1, gamma1, beta1, 1.f / N_IN, ss1);

        dim3 cgrid((R_PAIRS + OLD_TILES * 64 - 1) / (OLD_TILES * 64), K_OFF);
        conv12_atomic_kernel<<<cgrid, 256, 0, stream>>>(x, W1, W2, in_idx1, out_idx1, ss1, y1f, out);

        bn_stats_kernel<128><<<1024, 256, 0, stream>>>(y1f, N_OUT, sums2);
        bn_finalize_kernel<128><<<1, 128, 0, stream>>>(sums2, gamma2, beta2, 1.f / N_OUT, ss2);

        convs_atomic_kernel<<<cgrid, 256, 0, stream>>>(y1f, Ws, in_idx_s, out_idx_s, ss2, out);
        return;
    }

    bf16*  y1      = (bf16*)(ws + off_y1);
    bf16*  y2b     = (bf16*)(ws + off_y2b);
    float* sums1   = (float*)(ws + off_stats);    // [256]
    float* ss1     = sums1 + 256;                 // [256]
    float* ss2     = sums1 + 512;                 // [256]
    float* s2s     = (float*)(ws + off_s2s);      // [64][256]
    u32*   counts  = (u32*)(ws + off_counts);
    u32*   kstart  = (u32*)(ws + off_kstart);
    u32*   bsum    = (u32*)(ws + off_bsum);
    u32*   list    = (u32*)(ws + off_list);
    bf16*  wf12    = (bf16*)(ws + off_wf12);
    bf16*  wfs     = (bf16*)(ws + off_wfs);

    int nblk = (N_OUT + BM - 1) / BM;    // 3907

    // ---- init ----
    hipMemsetAsync(ws + off_stats, 0, off_counts - off_stats, stream);   // stats + s2s
    hipMemsetAsync(counts, 0, 4ull * NB2, stream);

    // ---- merged rulebook sort (both in one 2M-bin pipeline) ----
    hist2_kernel<<<1024, 256, 0, stream>>>(out_idx1, out_idx_s, counts);
    scan1_kernel<<<NSB2, 256, 0, stream>>>(counts, bsum, NB2);
    scan2_kernel<<<1, 256, 0, stream>>>(bsum, kstart, NSB2, NB2);
    scan3_kernel<<<NSB2, 256, 0, stream>>>(counts, bsum, kstart, NB2);
    buildF2_kernel<<<(2 * NPAIRS + 255) / 256, 256, 0, stream>>>(
        in_idx1, out_idx1, in_idx_s, out_idx_s, kstart, counts, list);

    // ---- BN1 stats (apply fused into fused12's stage); weight prepack ----
    bn_stats_kernel<64><<<1024, 256, 0, stream>>>(x, N_IN, sums1);
    bn_finalize_kernel<64><<<1, 64, 0, stream>>>(sums1, gamma1, beta1, 1.f / N_IN, ss1);
    pack12_kernel<<<512, 256, 0, stream>>>(W1, W2, wf12);
    packS_kernel<<<512, 256, 0, stream>>>(Ws, wfs);

    // ---- fused conv1+conv2 (BN1+ReLU fused into stage) ----
    fused12_kernel<<<nblk, 512, 0, stream>>>(x, wf12, ss1, kstart, list, y1, y2b, s2s);
    bn_finalize2_kernel<<<1, 128, 0, stream>>>(s2s, gamma2, beta2, ss2);

    // ---- fused submanifold conv (BN2+ReLU fused into stage, +y2b epilogue) ----
    fusedS_kernel<<<nblk, 512, 0, stream>>>(y1, wfs, ss2, kstart + NBINS_KC, list, y2b, out);
}